// Round 1
// baseline (1161.250 us; speedup 1.0000x reference)
//
#include <hip/hip_runtime.h>
#include <hip/hip_bf16.h>

#define NN     50000
#define NEDGE  1600000
#define NG     512
#define FIN    128
#define FHID   128
#define FPROJ  256

typedef __attribute__((ext_vector_type(8))) short short8;
typedef __attribute__((ext_vector_type(4))) float f32x4;

static __device__ __forceinline__ short f2bf(float f) {
    union { float f; unsigned u; } x; x.f = f;
    unsigned r = (x.u + 0x7FFFu + ((x.u >> 16) & 1u)) >> 16;
    return (short)(r & 0xFFFFu);
}
static __device__ __forceinline__ float bf2f(unsigned short u) {
    union { unsigned u; float f; } x; x.u = ((unsigned)u) << 16;
    return x.f;
}

// ---------------- CSR build ----------------

__global__ void k_hist(const int* __restrict__ dst, int* __restrict__ cnt) {
    int i = blockIdx.x * 256 + threadIdx.x;
    if (i < NEDGE) atomicAdd(&cnt[dst[i]], 1);
}

__global__ void k_scan1(const int* __restrict__ cnt, int* __restrict__ off,
                        int* __restrict__ bsum) {
    __shared__ int s[256];
    int i = blockIdx.x * 256 + threadIdx.x;
    int v = (i < NN) ? cnt[i] : 0;
    s[threadIdx.x] = v;
    for (int o = 1; o < 256; o <<= 1) {
        __syncthreads();
        int t = (threadIdx.x >= o) ? s[threadIdx.x - o] : 0;
        __syncthreads();
        s[threadIdx.x] += t;
    }
    __syncthreads();
    if (i < NN) off[i] = s[threadIdx.x] - v;              // exclusive
    if (threadIdx.x == 255) bsum[blockIdx.x] = s[255];
}

__global__ void k_scan2(int* __restrict__ bsum, int nb) {
    __shared__ int s[256];
    int v = (threadIdx.x < nb) ? bsum[threadIdx.x] : 0;
    s[threadIdx.x] = v;
    for (int o = 1; o < 256; o <<= 1) {
        __syncthreads();
        int t = (threadIdx.x >= o) ? s[threadIdx.x - o] : 0;
        __syncthreads();
        s[threadIdx.x] += t;
    }
    __syncthreads();
    if (threadIdx.x < nb) bsum[threadIdx.x] = s[threadIdx.x] - v;  // exclusive
}

__global__ void k_scan3(int* __restrict__ off, const int* __restrict__ bsum,
                        const int* __restrict__ cnt, float* __restrict__ dinv) {
    int i = blockIdx.x * 256 + threadIdx.x;
    if (i < NN) {
        off[i] += bsum[blockIdx.x];
        dinv[i] = 1.0f / sqrtf((float)(cnt[i] + 1));  // deg = in-deg + self-loop
    }
    if (i == 0) off[NN] = NEDGE;
}

__global__ void k_fill(const int* __restrict__ src, const int* __restrict__ dst,
                       const int* __restrict__ off, int* __restrict__ cur,
                       int* __restrict__ csrc) {
    int i = blockIdx.x * 256 + threadIdx.x;
    if (i < NEDGE) {
        int d = dst[i];
        int p = off[d] + atomicAdd(&cur[d], 1);
        csrc[p] = src[i];
    }
}

// ---------------- MFMA GEMM:  hp[i,:] = bf16( (A[i,:] @ W) * dinv[i] ) ----------------

// W fragment prep: layout [(nt*4+kt)*64 + lane]*8 + j  holds  W[kt*32+(lane>>4)*8+j][nt*16+(lane&15)]
__global__ void k_prepw(const float* __restrict__ W, short* __restrict__ Wf) {
    int nt = blockIdx.x >> 2, kt = blockIdx.x & 3;
    int lane = threadIdx.x;
    int n = nt * 16 + (lane & 15);
    int kbase = kt * 32 + (lane >> 4) * 8;
    short8 v;
#pragma unroll
    for (int j = 0; j < 8; ++j) v[j] = f2bf(W[(kbase + j) * FHID + n]);
    *(short8*)(Wf + (size_t)((nt * 4 + kt) * 64 + lane) * 8) = v;
}

__global__ __launch_bounds__(256) void k_gemm(const float* __restrict__ A,
                                              const short* __restrict__ Wf,
                                              const float* __restrict__ dinv,
                                              unsigned short* __restrict__ hp) {
    int lane = threadIdx.x & 63;
    int wv = threadIdx.x >> 6;
    int quad = lane >> 4;
    int rowbase = blockIdx.x * 64 + wv * 16;
    int arow = rowbase + (lane & 15);
    if (arow >= NN) arow = NN - 1;
    const float* Ap = A + (size_t)arow * FIN;

    f32x4 acc[8];
#pragma unroll
    for (int i = 0; i < 8; ++i) acc[i] = (f32x4){0.f, 0.f, 0.f, 0.f};

#pragma unroll
    for (int kt = 0; kt < 4; ++kt) {
        const float* ap = Ap + kt * 32 + quad * 8;
        float4 a0 = *(const float4*)ap;
        float4 a1 = *(const float4*)(ap + 4);
        short8 af;
        af[0] = f2bf(a0.x); af[1] = f2bf(a0.y); af[2] = f2bf(a0.z); af[3] = f2bf(a0.w);
        af[4] = f2bf(a1.x); af[5] = f2bf(a1.y); af[6] = f2bf(a1.z); af[7] = f2bf(a1.w);
#pragma unroll
        for (int nt = 0; nt < 8; ++nt) {
            short8 bf = *(const short8*)(Wf + (size_t)((nt * 4 + kt) * 64 + lane) * 8);
            acc[nt] = __builtin_amdgcn_mfma_f32_16x16x32_bf16(af, bf, acc[nt], 0, 0, 0);
        }
    }
    // C/D layout: col = lane&15, row = quad*4 + reg   [measured m89/m91]
    float4 dv = *(const float4*)(dinv + rowbase + quad * 4);
    float dvv[4] = {dv.x, dv.y, dv.z, dv.w};
    int col = lane & 15;
#pragma unroll
    for (int r = 0; r < 4; ++r) {
        int orow = rowbase + quad * 4 + r;
        if (orow < NN) {
#pragma unroll
            for (int nt = 0; nt < 8; ++nt)
                hp[(size_t)orow * FHID + nt * 16 + col] =
                    (unsigned short)f2bf(acc[nt][r] * dvv[r]);
        }
    }
}

// ---------------- Aggregate: h_out[d] = relu(dinv[d]*(hp[d]+sum_{s in N(d)} hp[s]) + b) [+resid] --------

__global__ __launch_bounds__(256) void k_agg(const unsigned* __restrict__ hp2,
                                             const int* __restrict__ off,
                                             const int* __restrict__ csrc,
                                             const float* __restrict__ dinv,
                                             const float* __restrict__ bias,
                                             const float* __restrict__ resid,
                                             float* __restrict__ hout) {
    int node = blockIdx.x * 4 + (threadIdx.x >> 6);   // one wave per node
    int lane = threadIdx.x & 63;                      // 2 features per lane
    int beg = off[node], end = off[node + 1];

    unsigned self = hp2[(size_t)node * 64 + lane];
    float a0 = bf2f((unsigned short)(self & 0xFFFFu));
    float a1 = bf2f((unsigned short)(self >> 16));

    int e = beg;
    for (; e + 4 <= end; e += 4) {
        int s0 = csrc[e], s1 = csrc[e + 1], s2 = csrc[e + 2], s3 = csrc[e + 3];
        unsigned v0 = hp2[(size_t)s0 * 64 + lane];
        unsigned v1 = hp2[(size_t)s1 * 64 + lane];
        unsigned v2 = hp2[(size_t)s2 * 64 + lane];
        unsigned v3 = hp2[(size_t)s3 * 64 + lane];
        a0 += bf2f((unsigned short)(v0 & 0xFFFFu)) + bf2f((unsigned short)(v1 & 0xFFFFu))
            + bf2f((unsigned short)(v2 & 0xFFFFu)) + bf2f((unsigned short)(v3 & 0xFFFFu));
        a1 += bf2f((unsigned short)(v0 >> 16)) + bf2f((unsigned short)(v1 >> 16))
            + bf2f((unsigned short)(v2 >> 16)) + bf2f((unsigned short)(v3 >> 16));
    }
    for (; e < end; ++e) {
        unsigned v = hp2[(size_t)csrc[e] * 64 + lane];
        a0 += bf2f((unsigned short)(v & 0xFFFFu));
        a1 += bf2f((unsigned short)(v >> 16));
    }
    float dv = dinv[node];
    float2 b = *((const float2*)bias + lane);
    float o0 = fmaxf(a0 * dv + b.x, 0.f);
    float o1 = fmaxf(a1 * dv + b.y, 0.f);
    if (resid) {
        float2 rr = *((const float2*)(resid + (size_t)node * FHID) + lane);
        o0 += rr.x; o1 += rr.y;
    }
    *((float2*)(hout + (size_t)node * FHID) + lane) = make_float2(o0, o1);
}

// ---------------- Pooling ----------------

__global__ void k_starts(const int* __restrict__ batch, int* __restrict__ starts) {
    int i = blockIdx.x * 256 + threadIdx.x;
    if (i >= NN) return;
    int b = batch[i];
    if (i == 0) {
        for (int g = 0; g <= b; ++g) starts[g] = 0;
    } else {
        int p = batch[i - 1];
        for (int g = p + 1; g <= b; ++g) starts[g] = i;
    }
    if (i == NN - 1) {
        for (int g = b + 1; g <= NG; ++g) starts[g] = NN;
    }
}

__global__ void k_pool(const float* __restrict__ h, const int* __restrict__ starts,
                       float* __restrict__ pooled) {
    int g = blockIdx.x, c = threadIdx.x;
    int beg = starts[g], end = starts[g + 1];
    float s = 0.f;
    for (int i = beg; i < end; ++i) s += h[(size_t)i * FHID + c];
    int cnt = end - beg;
    pooled[g * FHID + c] = s / (float)(cnt > 0 ? cnt : 1);
}

// ---------------- Small MLP / BN heads (M = 512 rows) ----------------

__global__ void k_mlp(const float* __restrict__ A, const float* __restrict__ W,
                      const float* __restrict__ bias, float* __restrict__ out,
                      int K, int Nc, int act) {
    __shared__ float As[8 * 256];
    int n = threadIdx.x;                 // blockDim.x == Nc
    int r0 = blockIdx.x * 8;
    for (int idx = n; idx < 8 * K; idx += blockDim.x) As[idx] = A[(size_t)r0 * K + idx];
    __syncthreads();
    float bb = bias[n];
    float acc[8];
#pragma unroll
    for (int r = 0; r < 8; ++r) acc[r] = bb;
    for (int k = 0; k < K; ++k) {
        float w = W[(size_t)k * Nc + n];
#pragma unroll
        for (int r = 0; r < 8; ++r) acc[r] = fmaf(As[r * K + k], w, acc[r]);
    }
#pragma unroll
    for (int r = 0; r < 8; ++r) {
        float v = acc[r];
        if (act) v = fmaxf(v, 0.f);
        out[(size_t)(r0 + r) * Nc + n] = v;
    }
}

__global__ void k_bnsum(const float* __restrict__ X, float* __restrict__ stats, int Nc) {
    int c = threadIdx.x;                 // blockDim.x == Nc
    int r0 = blockIdx.x * 32;
    float s = 0.f, q = 0.f;
    for (int r = r0; r < r0 + 32; ++r) {
        float v = X[(size_t)r * Nc + c];
        s += v; q += v * v;
    }
    atomicAdd(&stats[c], s);
    atomicAdd(&stats[Nc + c], q);
}

__global__ void k_bnapply(const float* __restrict__ X, const float* __restrict__ stats,
                          const float* __restrict__ gamma, const float* __restrict__ beta,
                          float* __restrict__ out, int Nc, int act) {
    int i = blockIdx.x * 256 + threadIdx.x;
    if (i >= 512 * Nc) return;
    int c = i % Nc;
    float m = stats[c] * (1.f / 512.f);
    float var = stats[Nc + c] * (1.f / 512.f) - m * m;
    float inv = 1.0f / sqrtf(var + 1e-5f);
    float v = gamma[c] * (X[i] - m) * inv + beta[c];
    if (act) v = fmaxf(v, 0.f);
    out[i] = v;
}

// ---------------- Orchestration ----------------

extern "C" void kernel_launch(void* const* d_in, const int* in_sizes, int n_in,
                              void* d_out, int out_size, void* d_ws, size_t ws_size,
                              hipStream_t stream) {
    const float* x[2]     = {(const float*)d_in[0], (const float*)d_in[3]};
    const int*   ei[2]    = {(const int*)d_in[1], (const int*)d_in[4]};
    const int*   batch[2] = {(const int*)d_in[2], (const int*)d_in[5]};
    const float* W[3]  = {(const float*)d_in[6], (const float*)d_in[8], (const float*)d_in[10]};
    const float* bb[3] = {(const float*)d_in[7], (const float*)d_in[9], (const float*)d_in[11]};
    const float* Wp1 = (const float*)d_in[12]; const float* bp1 = (const float*)d_in[13];
    const float* g1  = (const float*)d_in[14]; const float* be1 = (const float*)d_in[15];
    const float* Wp2 = (const float*)d_in[16]; const float* bp2 = (const float*)d_in[17];
    const float* g2  = (const float*)d_in[18]; const float* be2 = (const float*)d_in[19];
    const float* Wq1 = (const float*)d_in[20]; const float* bq1 = (const float*)d_in[21];
    const float* Wq2 = (const float*)d_in[22]; const float* bq2 = (const float*)d_in[23];

    char* ws = (char*)d_ws;
    size_t off = 0;
    auto alloc = [&](size_t bytes) -> void* {
        void* p = ws + off;
        off += (bytes + 255) & ~(size_t)255;
        return p;
    };
    float*          h_cur  = (float*)alloc((size_t)NN * FHID * 4);
    unsigned short* hp     = (unsigned short*)alloc((size_t)NN * FHID * 2);
    int*            csrc   = (int*)alloc((size_t)NEDGE * 4);
    int*            csroff = (int*)alloc((size_t)(NN + 1) * 4);
    int*            cnt    = (int*)alloc((size_t)NN * 4);
    int*            cur    = (int*)alloc((size_t)NN * 4);
    float*          dinv   = (float*)alloc((size_t)50048 * 4);   // padded for gemm epilogue
    int*            bsum   = (int*)alloc(256 * 4);
    int*            starts = (int*)alloc((NG + 1) * 4);
    float*          pooled = (float*)alloc((size_t)2 * NG * FHID * 4);
    short*          Wf     = (short*)alloc((size_t)3 * 16384 * 2);
    float*          t1     = (float*)alloc((size_t)512 * 256 * 4);
    float*          t2     = (float*)alloc((size_t)512 * 256 * 4);
    float*          t3     = (float*)alloc((size_t)512 * 128 * 4);
    float*          stats  = (float*)alloc(2 * 256 * 4);

    for (int l = 0; l < 3; ++l)
        k_prepw<<<32, 64, 0, stream>>>(W[l], Wf + (size_t)l * 16384);

    for (int e = 0; e < 2; ++e) {
        hipMemsetAsync(cnt, 0, (size_t)NN * 4, stream);
        hipMemsetAsync(cur, 0, (size_t)NN * 4, stream);
        const int* src = ei[e];
        const int* dst = ei[e] + NEDGE;
        k_hist<<<(NEDGE + 255) / 256, 256, 0, stream>>>(dst, cnt);
        k_scan1<<<196, 256, 0, stream>>>(cnt, csroff, bsum);
        k_scan2<<<1, 256, 0, stream>>>(bsum, 196);
        k_scan3<<<196, 256, 0, stream>>>(csroff, bsum, cnt, dinv);
        k_fill<<<(NEDGE + 255) / 256, 256, 0, stream>>>(src, dst, csroff, cur, csrc);

        for (int l = 0; l < 3; ++l) {
            const float* Ain = (l == 0) ? x[e] : h_cur;
            k_gemm<<<782, 256, 0, stream>>>(Ain, Wf + (size_t)l * 16384, dinv, hp);
            k_agg<<<NN / 4, 256, 0, stream>>>((const unsigned*)hp, csroff, csrc, dinv,
                                              bb[l], (l == 0) ? nullptr : h_cur, h_cur);
        }
        k_starts<<<196, 256, 0, stream>>>(batch[e], starts);
        k_pool<<<NG, 128, 0, stream>>>(h_cur, starts, pooled + (size_t)e * NG * FHID);
    }

    float* outp = (float*)d_out;
    for (int e = 0; e < 2; ++e) {
        float* p_out = outp + (size_t)e * NG * FPROJ;
        float* z_out = outp + (size_t)(2 + e) * NG * FPROJ;
        // t1 = pooled @ Wp1 + bp1   [512,256]
        k_mlp<<<64, 256, 0, stream>>>(pooled + (size_t)e * NG * FHID, Wp1, bp1, t1, 128, 256, 0);
        hipMemsetAsync(stats, 0, 2 * 256 * 4, stream);
        k_bnsum<<<16, 256, 0, stream>>>(t1, stats, 256);
        k_bnapply<<<512, 256, 0, stream>>>(t1, stats, g1, be1, t2, 256, 1);  // zpre
        // t1 = zpre @ Wp2 + bp2
        k_mlp<<<64, 256, 0, stream>>>(t2, Wp2, bp2, t1, 256, 256, 0);
        hipMemsetAsync(stats, 0, 2 * 256 * 4, stream);
        k_bnsum<<<16, 256, 0, stream>>>(t1, stats, 256);
        k_bnapply<<<512, 256, 0, stream>>>(t1, stats, g2, be2, z_out, 256, 0);  // z
        // predictor
        k_mlp<<<64, 128, 0, stream>>>(z_out, Wq1, bq1, t3, 256, 128, 1);
        k_mlp<<<64, 256, 0, stream>>>(t3, Wq2, bq2, p_out, 128, 256, 0);
    }
}

// Round 2
// 1095.691 us; speedup vs baseline: 1.0598x; 1.0598x over previous
//
#include <hip/hip_runtime.h>
#include <hip/hip_bf16.h>

#define NN     50000
#define NEDGE  1600000
#define NG     512
#define FIN    128
#define FHID   128
#define FPROJ  256

typedef __attribute__((ext_vector_type(8))) short short8;
typedef __attribute__((ext_vector_type(4))) float f32x4;

static __device__ __forceinline__ short f2bf(float f) {
    union { float f; unsigned u; } x; x.f = f;
    unsigned r = (x.u + 0x7FFFu + ((x.u >> 16) & 1u)) >> 16;
    return (short)(r & 0xFFFFu);
}
static __device__ __forceinline__ float bf2f(unsigned short u) {
    union { unsigned u; float f; } x; x.u = ((unsigned)u) << 16;
    return x.f;
}

// ---------------- CSR build ----------------

// one atomic pass: count + per-edge rank within its dst bucket
__global__ void k_histrank(const int* __restrict__ dst, int* __restrict__ cnt,
                           unsigned short* __restrict__ rank) {
    int i = blockIdx.x * 256 + threadIdx.x;
    if (i < NEDGE) rank[i] = (unsigned short)atomicAdd(&cnt[dst[i]], 1);
}

__global__ void k_scan1(const int* __restrict__ cnt, int* __restrict__ off,
                        int* __restrict__ bsum) {
    __shared__ int s[256];
    int i = blockIdx.x * 256 + threadIdx.x;
    int v = (i < NN) ? cnt[i] : 0;
    s[threadIdx.x] = v;
    for (int o = 1; o < 256; o <<= 1) {
        __syncthreads();
        int t = (threadIdx.x >= o) ? s[threadIdx.x - o] : 0;
        __syncthreads();
        s[threadIdx.x] += t;
    }
    __syncthreads();
    if (i < NN) off[i] = s[threadIdx.x] - v;              // exclusive
    if (threadIdx.x == 255) bsum[blockIdx.x] = s[255];
}

__global__ void k_scan2(int* __restrict__ bsum, int nb) {
    __shared__ int s[256];
    int v = (threadIdx.x < nb) ? bsum[threadIdx.x] : 0;
    s[threadIdx.x] = v;
    for (int o = 1; o < 256; o <<= 1) {
        __syncthreads();
        int t = (threadIdx.x >= o) ? s[threadIdx.x - o] : 0;
        __syncthreads();
        s[threadIdx.x] += t;
    }
    __syncthreads();
    if (threadIdx.x < nb) bsum[threadIdx.x] = s[threadIdx.x] - v;  // exclusive
}

__global__ void k_scan3(int* __restrict__ off, const int* __restrict__ bsum,
                        const int* __restrict__ cnt, float* __restrict__ dinv) {
    int i = blockIdx.x * 256 + threadIdx.x;
    if (i < NN) {
        off[i] += bsum[blockIdx.x];
        dinv[i] = 1.0f / sqrtf((float)(cnt[i] + 1));  // deg = in-deg + self-loop
    }
    if (i == 0) off[NN] = NEDGE;
}

// atomic-free scatter using precomputed rank
__global__ void k_scatter(const int* __restrict__ src, const int* __restrict__ dst,
                          const int* __restrict__ off,
                          const unsigned short* __restrict__ rank,
                          int* __restrict__ csrc) {
    int i = blockIdx.x * 256 + threadIdx.x;
    if (i < NEDGE) csrc[off[dst[i]] + (int)rank[i]] = src[i];
}

// ---------------- MFMA GEMM:  hp[i,:] = bf16( (A[i,:] @ W) * dinv[i] ) ----------------
// hp stored as two 64-feature planes: hp[p*NN*64 + node*64 + c]  (c = feat - p*64)

__global__ void k_prepw(const float* __restrict__ W, short* __restrict__ Wf) {
    int nt = blockIdx.x >> 2, kt = blockIdx.x & 3;
    int lane = threadIdx.x;
    int n = nt * 16 + (lane & 15);
    int kbase = kt * 32 + (lane >> 4) * 8;
    short8 v;
#pragma unroll
    for (int j = 0; j < 8; ++j) v[j] = f2bf(W[(kbase + j) * FHID + n]);
    *(short8*)(Wf + (size_t)((nt * 4 + kt) * 64 + lane) * 8) = v;
}

__global__ __launch_bounds__(256) void k_gemm(const float* __restrict__ A,
                                              const short* __restrict__ Wf,
                                              const float* __restrict__ dinv,
                                              unsigned short* __restrict__ hp) {
    int lane = threadIdx.x & 63;
    int wv = threadIdx.x >> 6;
    int quad = lane >> 4;
    int rowbase = blockIdx.x * 64 + wv * 16;
    int arow = rowbase + (lane & 15);
    if (arow >= NN) arow = NN - 1;
    const float* Ap = A + (size_t)arow * FIN;

    f32x4 acc[8];
#pragma unroll
    for (int i = 0; i < 8; ++i) acc[i] = (f32x4){0.f, 0.f, 0.f, 0.f};

#pragma unroll
    for (int kt = 0; kt < 4; ++kt) {
        const float* ap = Ap + kt * 32 + quad * 8;
        float4 a0 = *(const float4*)ap;
        float4 a1 = *(const float4*)(ap + 4);
        short8 af;
        af[0] = f2bf(a0.x); af[1] = f2bf(a0.y); af[2] = f2bf(a0.z); af[3] = f2bf(a0.w);
        af[4] = f2bf(a1.x); af[5] = f2bf(a1.y); af[6] = f2bf(a1.z); af[7] = f2bf(a1.w);
#pragma unroll
        for (int nt = 0; nt < 8; ++nt) {
            short8 bf = *(const short8*)(Wf + (size_t)((nt * 4 + kt) * 64 + lane) * 8);
            acc[nt] = __builtin_amdgcn_mfma_f32_16x16x32_bf16(af, bf, acc[nt], 0, 0, 0);
        }
    }
    // C/D layout: col = lane&15, row = quad*4 + reg   [measured m89/m91]
    float4 dv = *(const float4*)(dinv + rowbase + quad * 4);
    float dvv[4] = {dv.x, dv.y, dv.z, dv.w};
    int col = lane & 15;
#pragma unroll
    for (int r = 0; r < 4; ++r) {
        int orow = rowbase + quad * 4 + r;
        if (orow < NN) {
#pragma unroll
            for (int nt = 0; nt < 8; ++nt) {
                int c = nt * 16 + col;
                int plane = c >> 6, cc = c & 63;
                hp[(size_t)plane * NN * 64 + (size_t)orow * 64 + cc] =
                    (unsigned short)f2bf(acc[nt][r] * dvv[r]);
            }
        }
    }
}

// ------- Aggregate one 64-feature plane:
// hout[d, p*64:] = relu(dinv[d]*(hp_p[d]+sum_{s in N(d)} hp_p[s]) + b_p) [+resid]
// 32 lanes per node (2 bf16 feats per lane); 8 nodes per 256-thread block.

__global__ __launch_bounds__(256) void k_aggh(const unsigned* __restrict__ hp,
                                              int plane,
                                              const int* __restrict__ off,
                                              const int* __restrict__ csrc,
                                              const float* __restrict__ dinv,
                                              const float* __restrict__ bias,
                                              const float* __restrict__ resid,
                                              float* __restrict__ hout) {
    int tid = threadIdx.x;
    int l2 = tid & 31;
    int node = blockIdx.x * 8 + (tid >> 5);   // 6250 blocks * 8 = 50000 exactly
    const unsigned* base = hp + (size_t)plane * NN * 32;
    int beg = off[node], end = off[node + 1];

    unsigned self = base[(size_t)node * 32 + l2];
    float a0 = bf2f((unsigned short)(self & 0xFFFFu));
    float a1 = bf2f((unsigned short)(self >> 16));

    int e = beg;
    for (; e + 4 <= end; e += 4) {
        int s0 = csrc[e], s1 = csrc[e + 1], s2 = csrc[e + 2], s3 = csrc[e + 3];
        unsigned v0 = base[(size_t)s0 * 32 + l2];
        unsigned v1 = base[(size_t)s1 * 32 + l2];
        unsigned v2 = base[(size_t)s2 * 32 + l2];
        unsigned v3 = base[(size_t)s3 * 32 + l2];
        a0 += bf2f((unsigned short)(v0 & 0xFFFFu)) + bf2f((unsigned short)(v1 & 0xFFFFu))
            + bf2f((unsigned short)(v2 & 0xFFFFu)) + bf2f((unsigned short)(v3 & 0xFFFFu));
        a1 += bf2f((unsigned short)(v0 >> 16)) + bf2f((unsigned short)(v1 >> 16))
            + bf2f((unsigned short)(v2 >> 16)) + bf2f((unsigned short)(v3 >> 16));
    }
    for (; e < end; ++e) {
        unsigned v = base[(size_t)csrc[e] * 32 + l2];
        a0 += bf2f((unsigned short)(v & 0xFFFFu));
        a1 += bf2f((unsigned short)(v >> 16));
    }
    float dv = dinv[node];
    float2 b = *((const float2*)bias + plane * 32 + l2);
    float o0 = fmaxf(a0 * dv + b.x, 0.f);
    float o1 = fmaxf(a1 * dv + b.y, 0.f);
    if (resid) {
        float2 rr = *((const float2*)(resid + (size_t)node * FHID + plane * 64) + l2);
        o0 += rr.x; o1 += rr.y;
    }
    *((float2*)(hout + (size_t)node * FHID + plane * 64) + l2) = make_float2(o0, o1);
}

// ---------------- Pooling ----------------

__global__ void k_starts(const int* __restrict__ batch, int* __restrict__ starts) {
    int i = blockIdx.x * 256 + threadIdx.x;
    if (i >= NN) return;
    int b = batch[i];
    if (i == 0) {
        for (int g = 0; g <= b; ++g) starts[g] = 0;
    } else {
        int p = batch[i - 1];
        for (int g = p + 1; g <= b; ++g) starts[g] = i;
    }
    if (i == NN - 1) {
        for (int g = b + 1; g <= NG; ++g) starts[g] = NN;
    }
}

__global__ void k_pool(const float* __restrict__ h, const int* __restrict__ starts,
                       float* __restrict__ pooled) {
    int g = blockIdx.x, c = threadIdx.x;
    int beg = starts[g], end = starts[g + 1];
    float s = 0.f;
    for (int i = beg; i < end; ++i) s += h[(size_t)i * FHID + c];
    int cnt = end - beg;
    pooled[g * FHID + c] = s / (float)(cnt > 0 ? cnt : 1);
}

// ---------------- Fused MLP / BN heads (M = 512 rows) ----------------
// out = [relu?]( bnin?(A) @ W + bias );  optional BN-stats accumulation of raw out.
// statsIn layout: [K sums][K sqsums]; statsOut layout: [Nc sums][Nc sqsums]

__global__ void k_mlp(const float* __restrict__ A, const float* __restrict__ W,
                      const float* __restrict__ bias, float* __restrict__ out,
                      int K, int Nc, int act,
                      float* __restrict__ statsOut,
                      const float* __restrict__ statsIn,
                      const float* __restrict__ gIn, const float* __restrict__ beIn) {
    __shared__ float As[8 * 256];
    __shared__ float scl[256], shf[256];
    int n = threadIdx.x;                 // blockDim.x == Nc
    int r0 = blockIdx.x * 8;
    if (statsIn && n < K) {
        float m = statsIn[n] * (1.f / 512.f);
        float var = statsIn[K + n] * (1.f / 512.f) - m * m;
        float inv = 1.0f / sqrtf(var + 1e-5f);
        float s = gIn[n] * inv;
        scl[n] = s;
        shf[n] = beIn[n] - m * s;
    }
    __syncthreads();
    for (int idx = n; idx < 8 * K; idx += blockDim.x) {
        float v = A[(size_t)r0 * K + idx];
        if (statsIn) {
            int k = idx & (K - 1);       // K is 128 or 256
            v = fmaxf(v * scl[k] + shf[k], 0.f);   // relu(BN1(.)) input transform
        }
        As[idx] = v;
    }
    __syncthreads();
    float bb = bias[n];
    float acc[8];
#pragma unroll
    for (int r = 0; r < 8; ++r) acc[r] = bb;
    for (int k = 0; k < K; ++k) {
        float w = W[(size_t)k * Nc + n];
#pragma unroll
        for (int r = 0; r < 8; ++r) acc[r] = fmaf(As[r * K + k], w, acc[r]);
    }
    if (statsOut) {
        float s = 0.f, q = 0.f;
#pragma unroll
        for (int r = 0; r < 8; ++r) { s += acc[r]; q += acc[r] * acc[r]; }
        atomicAdd(&statsOut[n], s);
        atomicAdd(&statsOut[Nc + n], q);
    }
#pragma unroll
    for (int r = 0; r < 8; ++r) {
        float v = acc[r];
        if (act) v = fmaxf(v, 0.f);
        out[(size_t)(r0 + r) * Nc + n] = v;
    }
}

__global__ void k_bnapply(const float* __restrict__ X, const float* __restrict__ stats,
                          const float* __restrict__ gamma, const float* __restrict__ beta,
                          float* __restrict__ out, int Nc, int act) {
    int i = blockIdx.x * 256 + threadIdx.x;
    if (i >= 512 * Nc) return;
    int c = i % Nc;
    float m = stats[c] * (1.f / 512.f);
    float var = stats[Nc + c] * (1.f / 512.f) - m * m;
    float inv = 1.0f / sqrtf(var + 1e-5f);
    float v = gamma[c] * (X[i] - m) * inv + beta[c];
    if (act) v = fmaxf(v, 0.f);
    out[i] = v;
}

// ---------------- Orchestration ----------------

extern "C" void kernel_launch(void* const* d_in, const int* in_sizes, int n_in,
                              void* d_out, int out_size, void* d_ws, size_t ws_size,
                              hipStream_t stream) {
    const float* x[2]     = {(const float*)d_in[0], (const float*)d_in[3]};
    const int*   ei[2]    = {(const int*)d_in[1], (const int*)d_in[4]};
    const int*   batch[2] = {(const int*)d_in[2], (const int*)d_in[5]};
    const float* W[3]  = {(const float*)d_in[6], (const float*)d_in[8], (const float*)d_in[10]};
    const float* bb[3] = {(const float*)d_in[7], (const float*)d_in[9], (const float*)d_in[11]};
    const float* Wp1 = (const float*)d_in[12]; const float* bp1 = (const float*)d_in[13];
    const float* g1  = (const float*)d_in[14]; const float* be1 = (const float*)d_in[15];
    const float* Wp2 = (const float*)d_in[16]; const float* bp2 = (const float*)d_in[17];
    const float* g2  = (const float*)d_in[18]; const float* be2 = (const float*)d_in[19];
    const float* Wq1 = (const float*)d_in[20]; const float* bq1 = (const float*)d_in[21];
    const float* Wq2 = (const float*)d_in[22]; const float* bq2 = (const float*)d_in[23];

    char* ws = (char*)d_ws;
    size_t off = 0;
    auto alloc = [&](size_t bytes) -> void* {
        void* p = ws + off;
        off += (bytes + 255) & ~(size_t)255;
        return p;
    };
    float*          h_cur  = (float*)alloc((size_t)NN * FHID * 4);
    unsigned short* hp     = (unsigned short*)alloc((size_t)NN * FHID * 2);
    int*            csrc   = (int*)alloc((size_t)NEDGE * 4);
    int*            csroff = (int*)alloc((size_t)(NN + 1) * 4);
    int*            cnt    = (int*)alloc((size_t)NN * 4);
    unsigned short* rank   = (unsigned short*)alloc((size_t)NEDGE * 2);
    float*          dinv   = (float*)alloc((size_t)50048 * 4);   // padded for gemm epilogue
    int*            bsum   = (int*)alloc(256 * 4);
    int*            starts = (int*)alloc((NG + 1) * 4);
    float*          pooled = (float*)alloc((size_t)2 * NG * FHID * 4);
    short*          Wf     = (short*)alloc((size_t)3 * 16384 * 2);
    float*          t1     = (float*)alloc((size_t)512 * 256 * 4);
    float*          t2     = (float*)alloc((size_t)512 * 256 * 4);
    float*          t3     = (float*)alloc((size_t)512 * 128 * 4);
    float*          stats  = (float*)alloc(4 * 256 * 4);  // [BN1: 256s+256q][BN2: 256s+256q]

    for (int l = 0; l < 3; ++l)
        k_prepw<<<32, 64, 0, stream>>>(W[l], Wf + (size_t)l * 16384);

    for (int e = 0; e < 2; ++e) {
        hipMemsetAsync(cnt, 0, (size_t)NN * 4, stream);
        const int* src = ei[e];
        const int* dst = ei[e] + NEDGE;
        k_histrank<<<(NEDGE + 255) / 256, 256, 0, stream>>>(dst, cnt, rank);
        k_scan1<<<196, 256, 0, stream>>>(cnt, csroff, bsum);
        k_scan2<<<1, 256, 0, stream>>>(bsum, 196);
        k_scan3<<<196, 256, 0, stream>>>(csroff, bsum, cnt, dinv);
        k_scatter<<<(NEDGE + 255) / 256, 256, 0, stream>>>(src, dst, csroff, rank, csrc);

        for (int l = 0; l < 3; ++l) {
            const float* Ain = (l == 0) ? x[e] : h_cur;
            const float* resid = (l == 0) ? nullptr : h_cur;
            k_gemm<<<782, 256, 0, stream>>>(Ain, Wf + (size_t)l * 16384, dinv, hp);
            k_aggh<<<6250, 256, 0, stream>>>((const unsigned*)hp, 0, csroff, csrc, dinv,
                                             bb[l], resid, h_cur);
            k_aggh<<<6250, 256, 0, stream>>>((const unsigned*)hp, 1, csroff, csrc, dinv,
                                             bb[l], resid, h_cur);
        }
        k_starts<<<196, 256, 0, stream>>>(batch[e], starts);
        k_pool<<<NG, 128, 0, stream>>>(h_cur, starts, pooled + (size_t)e * NG * FHID);
    }

    float* outp = (float*)d_out;
    for (int e = 0; e < 2; ++e) {
        float* p_out = outp + (size_t)e * NG * FPROJ;
        float* z_out = outp + (size_t)(2 + e) * NG * FPROJ;
        float* st1 = stats, *st2 = stats + 512;
        hipMemsetAsync(stats, 0, 4 * 256 * 4, stream);
        // t1 = pooled @ Wp1 + bp1 (raw) ; accumulate BN1 stats
        k_mlp<<<64, 256, 0, stream>>>(pooled + (size_t)e * NG * FHID, Wp1, bp1, t1,
                                      128, 256, 0, st1, nullptr, nullptr, nullptr);
        // t2 = relu(BN1(t1)) @ Wp2 + bp2 (raw) ; accumulate BN2 stats
        k_mlp<<<64, 256, 0, stream>>>(t1, Wp2, bp2, t2,
                                      256, 256, 0, st2, st1, g1, be1);
        // z = BN2(t2)
        k_bnapply<<<512, 256, 0, stream>>>(t2, st2, g2, be2, z_out, 256, 0);
        // predictor
        k_mlp<<<64, 128, 0, stream>>>(z_out, Wq1, bq1, t3,
                                      256, 128, 1, nullptr, nullptr, nullptr, nullptr);
        k_mlp<<<64, 256, 0, stream>>>(t3, Wq2, bq2, p_out,
                                      128, 256, 0, nullptr, nullptr, nullptr, nullptr);
    }
}